// Round 5
// baseline (499.026 us; speedup 1.0000x reference)
//
#include <hip/hip_runtime.h>
#include <stdint.h>
#include <math.h>

#define BB 256
#define VV 128
#define MM 256
#define TDIM 10
#define HH 1024
#define IN_DIM 35840
#define KSPLIT 16
#define KSLICE 2240   /* IN_DIM/KSPLIT */
#define BK 32
#define NCHUNK 70     /* KSLICE/BK */

using f32x4  = __attribute__((ext_vector_type(4))) float;
using bf16x8 = __attribute__((ext_vector_type(8))) short;

__device__ __forceinline__ unsigned short f2bf(float f) {
    unsigned int u = __float_as_uint(f);
    unsigned int r = (u + 0x7FFFu + ((u >> 16) & 1u)) >> 16;
    return (unsigned short)r;
}

// ---------------- K1: build pred_input in bf16 -------------------------
// 512 threads (8 waves, 2/SIMD). Gather loop: 4-way p-split, 64 iters,
// unroll 8, clamped UNCONDITIONAL loads so 8 loads pipeline per batch.
__global__ __launch_bounds__(512)
void k_build(const float* __restrict__ x, const float* __restrict__ memory,
             const int* __restrict__ timings, const float* __restrict__ msurp,
             const float* __restrict__ lastp, short* __restrict__ A)
{
    int b = blockIdx.x, t = threadIdx.x;
    __shared__ int t_s[MM], idx_s[MM], st_s[MM];
    __shared__ float s_surprise;

    if (t < MM) t_s[t] = (t == 0) ? 0 : timings[b*MM + t - 1] + 1;
    if (t < 64) {
        float v = x[b*VV + t] * lastp[b*VV + t]
                + x[b*VV + t + 64] * lastp[b*VV + t + 64];
        #pragma unroll
        for (int off = 32; off > 0; off >>= 1)
            v += __shfl_down(v, off, 64);
        if (t == 0) s_surprise = -logf(v + 1e-8f);
    }
    __syncthreads();

    if (t < MM) {
        int ti = t_s[t], cnt = 0;
        #pragma unroll 4
        for (int j = 0; j < MM; ++j) {
            int tj = t_s[j];
            cnt += (tj < ti) || (tj == ti && j < t);
        }
        idx_s[cnt] = t;
        st_s[cnt]  = ti;
    }
    __syncthreads();

    short* Ab = A + (size_t)b * IN_DIM;
    if (t < MM) {
        float invm = 1.f / ((float)st_s[MM-1] + 1.f);
        int st = st_s[t], src = idx_s[t];
        #pragma unroll
        for (int tt = 0; tt < TDIM; ++tt)
            Ab[32768 + t*TDIM + tt] = (short)f2bf((float)((st >> tt) & 1));
        Ab[35328 + t] = (short)f2bf((float)st * invm);
        float sv = (src == 0) ? s_surprise : msurp[b*MM + src - 1] * 0.99f;
        Ab[35584 + t] = (short)f2bf(sv);
    }

    // gather memory rows -> A (sorted order). quarter q4 handles p = q4+4i.
    int q4 = t >> 7, v = t & (VV-1);
    float xv = x[b*VV + v];
    #pragma unroll 8
    for (int p = q4; p < MM; p += 4) {
        int src = idx_s[p];
        int row = (src == 0) ? 0 : src - 1;           // clamped, always valid
        float mv = memory[((size_t)b*MM + row)*VV + v];
        float val = (src == 0) ? xv : mv;
        Ab[p*VV + v] = (short)f2bf(val);
    }
}

// ---------------- K2: split-K bf16 MFMA GEMM, high-occupancy -----------
// grid (16, 64): x = k-split ks, y = n-tile xt of 32 cols (xt<32 -> W1,
// else Wg). BM=256, BN=32, BK=32. 512 threads = 8 waves; wave wv owns
// m-rows [wv*32, wv*32+32).
// THE R5 LEVER: 4 blocks/CU (32 waves, 100% wave occupancy) -- every
// prior schedule ran 2 blocks/CU and all were pinned at 131-146us with
// no pipe saturated (latency-bound, m233 regime). 4 independent barrier
// groups per CU fill each other's stage/wait stalls.
//   A: direct global->VGPR (L2-resident by XCD construction: blocks
//      sharing a ks land on one XCD; slice 1.15MB << 4MB L2).
//   W: reg-staged fp32 (coalesced, 2 chunks ahead) -> f2bf -> ds_write
//      into 2-ring LDS; frag reads 2x ds_read_b128 (R0-proven swizzle).
//   Sync: one lgkmcnt(0) + raw s_barrier per chunk; vmcnt never drained
//      in-loop (compiler inserts counted waits at first use).
// LDS: 2 x 2KB = 4KB. VGPR ~60 (acc 16 + af 16 + w 6 + addr).
__global__ __launch_bounds__(512, 8)
void k_gemm(const short* __restrict__ A, const float* __restrict__ W1,
            const float* __restrict__ Wg, float* __restrict__ P)
{
    int ks = blockIdx.x;          // 0..15
    int xt = blockIdx.y;          // 0..63
    const float* W = (xt < 32) ? W1 : Wg;
    int wcol0 = (xt & 31) * 32;
    int pcol0 = xt * 32;
    int k0 = ks * KSLICE;

    __shared__ bf16x8 Ws8[2][128];    // 4 KB

    int t = threadIdx.x;
    int l = t & 63, wv = t >> 6;          // wv 0..7
    int r = l & 15, q = l >> 4;

    // A row base pointers: lane (r,q) reads A[R][k0 + c*32 + q*8 .. +7]
    // as bf16x8 (16B aligned).
    const short* arow[2];
    #pragma unroll
    for (int mt = 0; mt < 2; ++mt) {
        int R = wv*32 + mt*16 + r;
        arow[mt] = A + (size_t)R*IN_DIM + k0 + q*8;
    }

    // W frag slots (chunk-invariant): col R, granule q, swz q^((R>>1)&3)
    int boff[2];
    #pragma unroll
    for (int nt = 0; nt < 2; ++nt) {
        int R = nt*16 + r;
        boff[nt] = R*4 + (q ^ ((R >> 1) & 3));
    }

    f32x4 acc[2][2];
    #pragma unroll
    for (int mt = 0; mt < 2; ++mt)
        #pragma unroll
        for (int nt = 0; nt < 2; ++nt)
            acc[mt][nt] = (f32x4){0.f, 0.f, 0.f, 0.f};

    // W staging: thread t -> col n = t&31, k-pair kb = (t>>5)*2 (+j, j<2).
    // Slot image matches frag reads: slot(n, g=kb>>3) swizzled, byte
    // (kb&7)*2 within the 16B slot -> one dword write per chunk.
    int wn  = t & 31;
    int wkb = (t >> 5) * 2;               // 0,2,...,30
    int wgr = wkb >> 3;
    int wslot16 = (wn*4 + (wgr ^ ((wn >> 1) & 3))) * 16 + (wkb & 7) * 2;
    const float* wbase = W + (size_t)(k0 + wkb)*HH + wcol0 + wn;

#define LOADA(AF, cc) do {                                                    \
        int ko_ = (cc)*BK;                                                    \
        _Pragma("unroll")                                                     \
        for (int mt_ = 0; mt_ < 2; ++mt_)                                     \
            AF[mt_] = *(const bf16x8*)(arow[mt_] + ko_);                      \
    } while (0)

#define WLOAD(wreg, cc) do {                                                  \
        const float* wp_ = wbase + (size_t)(cc)*BK*HH;                        \
        wreg[0] = wp_[0];                                                     \
        wreg[1] = wp_[HH];                                                    \
    } while (0)

#define WCONV(wreg, wdst) do {                                                \
        unsigned int dw_ = (unsigned int)f2bf(wreg[0])                        \
                         | ((unsigned int)f2bf(wreg[1]) << 16);               \
        *(unsigned int*)((char*)&Ws8[wdst][0] + wslot16) = dw_;               \
    } while (0)

    bf16x8 afA[2], afB[2];
    float wA[2], wB[2], w0[2];

    // ---- prologue ----
    WLOAD(w0, 0);
    LOADA(afA, 0);
    WLOAD(wA, 1);
    WCONV(w0, 0);                         // Ws[0] = W(0)
    asm volatile("s_waitcnt lgkmcnt(0)" ::: "memory");
    __builtin_amdgcn_s_barrier();

    // chunk c: MFMA(AF=A(c), Ws[c&1]); prefetch A(c+1)->AFN, W(c+2)->WNXT;
    // convert WCUR(=W(c+1)) into Ws[(c+1)&1]; lgkm-only barrier.
#define CHUNK(c, AF, AFN, WCUR, WNXT) do {                                    \
        int cA_ = ((c) + 1 < NCHUNK) ? (c) + 1 : NCHUNK - 1;                  \
        int cW_ = ((c) + 2 < NCHUNK) ? (c) + 2 : NCHUNK - 1;                  \
        LOADA(AFN, cA_);                                                      \
        WLOAD(WNXT, cW_);                                                     \
        {                                                                     \
            bf16x8 bf_[2];                                                    \
            _Pragma("unroll")                                                 \
            for (int nt = 0; nt < 2; ++nt) bf_[nt] = Ws8[(c) & 1][boff[nt]];  \
            _Pragma("unroll")                                                 \
            for (int mt = 0; mt < 2; ++mt)                                    \
                _Pragma("unroll")                                             \
                for (int nt = 0; nt < 2; ++nt)                                \
                    acc[mt][nt] = __builtin_amdgcn_mfma_f32_16x16x32_bf16(    \
                        AF[mt], bf_[nt], acc[mt][nt], 0, 0, 0);               \
        }                                                                     \
        WCONV(WCUR, ((c) + 1) & 1);                                           \
        asm volatile("s_waitcnt lgkmcnt(0)" ::: "memory");                    \
        __builtin_amdgcn_s_barrier();                                         \
    } while (0)

    #pragma unroll 1
    for (int c = 0; c < NCHUNK; c += 2) {
        CHUNK(c,     afA, afB, wA, wB);
        CHUNK(c + 1, afB, afA, wB, wA);
    }
#undef CHUNK
#undef WCONV
#undef WLOAD
#undef LOADA

    // epilogue: partials P[ks][m][2048]
    #pragma unroll
    for (int mt = 0; mt < 2; ++mt)
        #pragma unroll
        for (int nt = 0; nt < 2; ++nt)
            #pragma unroll
            for (int rg = 0; rg < 4; ++rg) {
                int m = wv*32 + mt*16 + q*4 + rg;
                int n = pcol0 + nt*16 + r;
                P[((size_t)ks*BB + m)*2048 + n] = acc[mt][nt][rg];
            }
}

// ---------------- K3: fused split-K reduce + gate + (h @ W2 + b2) ------
// 512 threads, one block per batch row. Phase 1: each thread sums one
// f32x4 quad of P over 16 k-splits (16 independent loads in flight).
// Phase 2: gate -> h in LDS. Phase 3: W2 matvec with 4-way k-split.
__global__ __launch_bounds__(512)
void k_tail(const float* __restrict__ P, const float* __restrict__ b1,
            const float* __restrict__ bg, const float* __restrict__ W2,
            const float* __restrict__ b2, float* __restrict__ out)
{
    int b = blockIdx.x, t = threadIdx.x;
    __shared__ f32x4 part[512];          // 8 KB
    __shared__ float hs[HH];             // 4 KB
    __shared__ float s2[512];            // 2 KB

    const f32x4* P4 = (const f32x4*)P;
    f32x4 s = (f32x4){0.f, 0.f, 0.f, 0.f};
    #pragma unroll
    for (int ks = 0; ks < KSPLIT; ++ks)
        s += P4[((size_t)ks*BB + b)*512 + t];
    part[t] = s;
    __syncthreads();

    if (t < 256) {
        f32x4 p1 = part[t]       + ((const f32x4*)b1)[t];
        f32x4 pg = part[t + 256] + ((const f32x4*)bg)[t];
        f32x4 o;
        #pragma unroll
        for (int j = 0; j < 4; ++j)
            o[j] = p1[j] / (1.f + expf(-pg[j]));
        ((f32x4*)hs)[t] = o;
    }
    __syncthreads();

    int v = t & 127, kh = t >> 7;        // 4-way k-split, 256 k each
    const float* wp = W2 + (size_t)kh*256*VV + v;
    const float* hk = hs + kh*256;
    float acc = 0.f;
    #pragma unroll 8
    for (int k = 0; k < 256; ++k)
        acc += hk[k] * wp[(size_t)k*VV];
    s2[t] = acc;
    __syncthreads();
    if (t < 128)
        out[(size_t)b*VV + v] = s2[t] + s2[t+128] + s2[t+256] + s2[t+384] + b2[v];
}

extern "C" void kernel_launch(void* const* d_in, const int* in_sizes, int n_in,
                              void* d_out, int out_size, void* d_ws, size_t ws_size,
                              hipStream_t stream)
{
    const float* x    = (const float*)d_in[0];
    const float* mem  = (const float*)d_in[1];
    const int*   tim  = (const int*)d_in[2];
    const float* msur = (const float*)d_in[3];
    const float* lp   = (const float*)d_in[4];
    const float* W1   = (const float*)d_in[5];
    const float* b1   = (const float*)d_in[6];
    const float* Wg   = (const float*)d_in[7];
    const float* bg   = (const float*)d_in[8];
    const float* W2   = (const float*)d_in[9];
    const float* b2   = (const float*)d_in[10];
    float* out = (float*)d_out;

    // ws layout: A bf16 [256][35840] | P fp32 [16][256][2048]
    short* A = (short*)d_ws;
    float* P = (float*)((char*)d_ws + 18350080);

    k_build <<<256, 512, 0, stream>>>(x, mem, tim, msur, lp, A);
    k_gemm  <<<dim3(KSPLIT, 64), 512, 0, stream>>>(A, W1, Wg, P);
    k_tail  <<<256, 512, 0, stream>>>(P, b1, bg, W2, b2, out);
}

// Round 6
// 479.758 us; speedup vs baseline: 1.0402x; 1.0402x over previous
//
#include <hip/hip_runtime.h>
#include <hip/hip_cooperative_groups.h>
#include <stdint.h>
#include <math.h>

namespace cg = cooperative_groups;

#define BB 256
#define VV 128
#define MM 256
#define TDIM 10
#define HH 1024
#define IN_DIM 35840
#define KSPLIT 16
#define KSLICE 2240   /* IN_DIM/KSPLIT */
#define BK 32
#define NCHUNK 70     /* KSLICE/BK */
#define BN 128        /* gemm n-cols per block; 16 xt tiles cover 2048 */

using f32x4  = __attribute__((ext_vector_type(4))) float;
using f32x2  = __attribute__((ext_vector_type(2))) float;
using bf16x8 = __attribute__((ext_vector_type(8))) short;
using u16x4  = __attribute__((ext_vector_type(4))) unsigned short;
using u64x2  = __attribute__((ext_vector_type(2))) unsigned long long;

__device__ __forceinline__ unsigned short f2bf(float f) {
    unsigned int u = __float_as_uint(f);
    unsigned int r = (u + 0x7FFFu + ((u >> 16) & 1u)) >> 16;
    return (unsigned short)r;
}

__device__ __forceinline__ void gload_lds16(const void* g, void* l) {
    __builtin_amdgcn_global_load_lds(
        (const __attribute__((address_space(1))) unsigned int*)g,
        (__attribute__((address_space(3))) unsigned int*)l,
        16, 0, 0);
}

// ---------------- shared-memory phase structs (union, max 48KB) --------
struct SmemBuild {
    int t_s[MM], idx_s[MM], st_s[MM];
    float s_surprise;
};
struct SmemGemm {
    bf16x8 As8[2][1024];              // 32 KB: A tile ring, R1-proven layout
    unsigned long long Wl[2][1024];   // 16 KB: W [n][k-slot] swizzled, 2 ring
};
struct SmemTail {
    f32x4 part[512];                  // 8 KB
    float hs[HH];                     // 4 KB
    float s2[512];                    // 2 KB
};
union SmemAll {
    SmemBuild b;
    SmemGemm  g;
    SmemTail  t;
};

// ---------------- phase 1: build pred_input in bf16 --------------------
__device__ __forceinline__ void phase_build(
    int b, int t, SmemBuild& sm,
    const float* __restrict__ x, const float* __restrict__ memory,
    const int* __restrict__ timings, const float* __restrict__ msurp,
    const float* __restrict__ lastp, short* __restrict__ A)
{
    if (t < MM) sm.t_s[t] = (t == 0) ? 0 : timings[b*MM + t - 1] + 1;
    if (t < 64) {
        float v = x[b*VV + t] * lastp[b*VV + t]
                + x[b*VV + t + 64] * lastp[b*VV + t + 64];
        #pragma unroll
        for (int off = 32; off > 0; off >>= 1)
            v += __shfl_down(v, off, 64);
        if (t == 0) sm.s_surprise = -logf(v + 1e-8f);
    }
    __syncthreads();

    if (t < MM) {
        int ti = sm.t_s[t], cnt = 0;
        #pragma unroll 4
        for (int j = 0; j < MM; ++j) {
            int tj = sm.t_s[j];
            cnt += (tj < ti) || (tj == ti && j < t);
        }
        sm.idx_s[cnt] = t;
        sm.st_s[cnt]  = ti;
    }
    __syncthreads();

    short* Ab = A + (size_t)b * IN_DIM;
    if (t < MM) {
        float invm = 1.f / ((float)sm.st_s[MM-1] + 1.f);
        int st = sm.st_s[t], src = sm.idx_s[t];
        #pragma unroll
        for (int tt = 0; tt < TDIM; ++tt)
            Ab[32768 + t*TDIM + tt] = (short)f2bf((float)((st >> tt) & 1));
        Ab[35328 + t] = (short)f2bf((float)st * invm);
        float sv = (src == 0) ? sm.s_surprise : msurp[b*MM + src - 1] * 0.99f;
        Ab[35584 + t] = (short)f2bf(sv);
    }

    int q4 = t >> 7, v = t & (VV-1);
    float xv = x[b*VV + v];
    #pragma unroll 8
    for (int p = q4; p < MM; p += 4) {
        int src = sm.idx_s[p];
        int row = (src == 0) ? 0 : src - 1;
        float mv = memory[((size_t)b*MM + row)*VV + v];
        float val = (src == 0) ? xv : mv;
        Ab[p*VV + v] = (short)f2bf(val);
    }
}

// ---------------- phase 2: split-K bf16 MFMA GEMM ----------------------
// bid -> ks = bid&15 (k-split), xt = bid>>4 (n-tile of 128; xt<8 W1 else Wg).
// Same-ks blocks (bid = ks+16*xt) land on one XCD -> A slice L2-resident.
// BM=256, BN=128, BK=32. 8 waves = 2M x 4N; wave tile 128m x 32n.
//   A: 2-ring LDS via global_load_lds, R1-proven swizzled layout.
//   W: GRANULARITY EXPERIMENT -- wave-per-k-row float2 loads = 512B
//      contiguous per row (prior rounds: 256B -> 1.35 TB/s, 128B -> 0.94).
//      4x2 reg transpose -> bf16 -> ds_write_b64 into [n][kslot^((n>>2)&7)]
//      (read conflicts exactly 2-way = free; write 8-way, off crit path).
//   Sync: per chunk issue 6 vmem (2 A-dma + 4 W), s_waitcnt vmcnt(6)
//      (drains prev chunk's 6, keeps this chunk's in flight), one
//      lgkmcnt(0)-guarded s_barrier. vmcnt never drains in-loop (T4).
__device__ __forceinline__ void phase_gemm(
    int bid, int t, SmemGemm& sm,
    const short* __restrict__ A, const float* __restrict__ W1,
    const float* __restrict__ Wg, float* __restrict__ P)
{
    int ks = bid & 15, xt = bid >> 4;
    const float* W = (xt < 8) ? W1 : Wg;
    int wcol0 = (xt & 7) * BN;
    int pcol0 = xt * BN;
    int k0 = ks * KSLICE;

    int l = t & 63, wv = t >> 6;
    int r = l & 15, q = l >> 4;
    int wm = wv >> 2, wn = wv & 3;

    // A frag slots (chunk-invariant)
    int aoff[8];
    #pragma unroll
    for (int mt = 0; mt < 8; ++mt) {
        int R = wm*128 + mt*16 + r;
        aoff[mt] = R*4 + (q ^ ((R >> 1) & 3));
    }
    // W frag u64 indices: n row, two swizzled 8B k-slots (2q, 2q+1)
    int widx[2][2];
    #pragma unroll
    for (int nt = 0; nt < 2; ++nt) {
        int n = wn*32 + nt*16 + r;
        int s = (n >> 2) & 7;
        widx[nt][0] = n*8 + ((2*q)     ^ s);
        widx[nt][1] = n*8 + ((2*q + 1) ^ s);
    }

    f32x4 acc[8][2];
    #pragma unroll
    for (int mt = 0; mt < 8; ++mt)
        #pragma unroll
        for (int nt = 0; nt < 2; ++nt)
            acc[mt][nt] = (f32x4){0.f, 0.f, 0.f, 0.f};

    // W staging maps: thread (wv,l): rows k0+c*BK+wv*4+j (j<4), cols l*2..+1
    const float* wbase = W + (size_t)(k0 + wv*4)*HH + wcol0 + l*2;
    int wrow0 = l*2;                       // n for i=0
    int wsA   = wv ^ ((l >> 1) & 7);       // swizzled slot (same both i)

#define STAGE_A(sbuf, cc) do {                                                \
        int kc_ = k0 + (cc)*BK;                                               \
        {   int G_ = t;                                                       \
            int m_ = G_ >> 2;                                                 \
            int kb_ = (G_ & 3) ^ ((m_ >> 1) & 3);                             \
            gload_lds16(A + (size_t)m_*IN_DIM + kc_ + kb_*8,                  \
                        (char*)&sm.As8[sbuf][0] + (size_t)(t & ~63)*16);      \
        }                                                                     \
        {   int G_ = t + 512;                                                 \
            int m_ = G_ >> 2;                                                 \
            int kb_ = (G_ & 3) ^ ((m_ >> 1) & 3);                             \
            gload_lds16(A + (size_t)m_*IN_DIM + kc_ + kb_*8,                  \
                        (char*)&sm.As8[sbuf][0] + (size_t)((t & ~63) + 512)*16);\
        }                                                                     \
    } while (0)

#define WLOAD(wr, cc) do {                                                    \
        const float* wp_ = wbase + (size_t)(cc)*BK*HH;                        \
        _Pragma("unroll")                                                     \
        for (int j_ = 0; j_ < 4; ++j_)                                        \
            wr[j_] = *(const f32x2*)(wp_ + (size_t)j_*HH);                    \
    } while (0)

#define WCONV(wr, wdst) do {                                                  \
        _Pragma("unroll")                                                     \
        for (int i_ = 0; i_ < 2; ++i_) {                                      \
            u16x4 pk_ = (u16x4){ f2bf(wr[0][i_]), f2bf(wr[1][i_]),            \
                                 f2bf(wr[2][i_]), f2bf(wr[3][i_]) };          \
            sm.Wl[wdst][(wrow0 + i_)*8 + wsA] =                               \
                __builtin_bit_cast(unsigned long long, pk_);                  \
        }                                                                     \
    } while (0)

    f32x2 wA[4], wB[4];

    // ---- prologue: A(0),W(0),A(1),W(1); drain first 6; conv W(0) ----
    STAGE_A(0, 0);
    WLOAD(wB, 0);
    STAGE_A(1, 1);
    WLOAD(wA, 1);
    asm volatile("s_waitcnt vmcnt(6)" ::: "memory");
    WCONV(wB, 0);
    asm volatile("s_waitcnt lgkmcnt(0)" ::: "memory");
    __builtin_amdgcn_s_barrier();

    // chunk c: stage A(c+1), load W(c+2); vmcnt(6) drains A(c)+W(c+1);
    // conv W(c+1) -> Wl[(c+1)&1]; frags+MFMA from ring slot c&1; barrier.
#define CHUNK(c, WCUR, WNXT) do {                                             \
        int cA_ = ((c) + 1 < NCHUNK) ? (c) + 1 : NCHUNK - 1;                  \
        int cW_ = ((c) + 2 < NCHUNK) ? (c) + 2 : NCHUNK - 1;                  \
        STAGE_A(((c) + 1) & 1, cA_);                                          \
        WLOAD(WNXT, cW_);                                                     \
        asm volatile("s_waitcnt vmcnt(6)" ::: "memory");                      \
        WCONV(WCUR, ((c) + 1) & 1);                                           \
        {                                                                     \
            int pb_ = (c) & 1;                                                \
            bf16x8 bf_[2];                                                    \
            _Pragma("unroll")                                                 \
            for (int nt = 0; nt < 2; ++nt) {                                  \
                u64x2 wv2_;                                                   \
                wv2_[0] = sm.Wl[pb_][widx[nt][0]];                            \
                wv2_[1] = sm.Wl[pb_][widx[nt][1]];                            \
                bf_[nt] = __builtin_bit_cast(bf16x8, wv2_);                   \
            }                                                                 \
            _Pragma("unroll")                                                 \
            for (int mt = 0; mt < 8; ++mt) {                                  \
                bf16x8 af_ = sm.As8[pb_][aoff[mt]];                           \
                _Pragma("unroll")                                             \
                for (int nt = 0; nt < 2; ++nt)                                \
                    acc[mt][nt] = __builtin_amdgcn_mfma_f32_16x16x32_bf16(    \
                        af_, bf_[nt], acc[mt][nt], 0, 0, 0);                  \
            }                                                                 \
        }                                                                     \
        asm volatile("s_waitcnt lgkmcnt(0)" ::: "memory");                    \
        __builtin_amdgcn_s_barrier();                                         \
    } while (0)

    #pragma unroll 1
    for (int c = 0; c < NCHUNK; c += 2) {
        CHUNK(c,     wA, wB);
        CHUNK(c + 1, wB, wA);
    }
#undef CHUNK
#undef WCONV
#undef WLOAD
#undef STAGE_A

    // epilogue: partials P[ks][m][2048] (plain stores, disjoint)
    #pragma unroll
    for (int mt = 0; mt < 8; ++mt)
        #pragma unroll
        for (int nt = 0; nt < 2; ++nt)
            #pragma unroll
            for (int rg = 0; rg < 4; ++rg) {
                int m = wm*128 + mt*16 + q*4 + rg;
                int n = pcol0 + wn*32 + nt*16 + r;
                P[((size_t)ks*BB + m)*2048 + n] = acc[mt][nt][rg];
            }
}

// ---------------- phase 3: split-K reduce + gate + (h @ W2 + b2) -------
__device__ __forceinline__ void phase_tail(
    int b, int t, SmemTail& sm,
    const float* __restrict__ P, const float* __restrict__ b1,
    const float* __restrict__ bg, const float* __restrict__ W2,
    const float* __restrict__ b2, float* __restrict__ out)
{
    const f32x4* P4 = (const f32x4*)P;
    f32x4 s = (f32x4){0.f, 0.f, 0.f, 0.f};
    #pragma unroll
    for (int ks = 0; ks < KSPLIT; ++ks)
        s += P4[((size_t)ks*BB + b)*512 + t];
    sm.part[t] = s;
    __syncthreads();

    if (t < 256) {
        f32x4 p1 = sm.part[t]       + ((const f32x4*)b1)[t];
        f32x4 pg = sm.part[t + 256] + ((const f32x4*)bg)[t];
        f32x4 o;
        #pragma unroll
        for (int j = 0; j < 4; ++j)
            o[j] = p1[j] / (1.f + expf(-pg[j]));
        ((f32x4*)sm.hs)[t] = o;
    }
    __syncthreads();

    int v = t & 127, kh = t >> 7;
    const float* wp = W2 + (size_t)kh*256*VV + v;
    const float* hk = sm.hs + kh*256;
    float acc = 0.f;
    #pragma unroll 8
    for (int k = 0; k < 256; ++k)
        acc += hk[k] * wp[(size_t)k*VV];
    sm.s2[t] = acc;
    __syncthreads();
    if (t < 128)
        out[(size_t)b*VV + v] = sm.s2[t] + sm.s2[t+128] + sm.s2[t+256]
                              + sm.s2[t+384] + b2[v];
}

// ---------------- fused cooperative kernel -----------------------------
__global__ __launch_bounds__(512, 2)
void k_fused(const float* __restrict__ x, const float* __restrict__ mem,
             const int* __restrict__ tim, const float* __restrict__ msur,
             const float* __restrict__ lp, const float* __restrict__ W1,
             const float* __restrict__ b1, const float* __restrict__ Wg,
             const float* __restrict__ bg, const float* __restrict__ W2,
             const float* __restrict__ b2, short* __restrict__ A,
             float* __restrict__ P, float* __restrict__ out)
{
    __shared__ SmemAll sm;
    int bid = blockIdx.x, t = threadIdx.x;

    phase_build(bid, t, sm.b, x, mem, tim, msur, lp, A);
    cg::this_grid().sync();
    phase_gemm(bid, t, sm.g, A, W1, Wg, P);
    cg::this_grid().sync();
    phase_tail(bid, t, sm.t, P, b1, bg, W2, b2, out);
}

// ---------------- standalone fallbacks (non-cooperative path) ----------
__global__ __launch_bounds__(512)
void k_build_s(const float* x, const float* mem, const int* tim,
               const float* msur, const float* lp, short* A)
{
    __shared__ SmemAll sm;
    phase_build(blockIdx.x, threadIdx.x, sm.b, x, mem, tim, msur, lp, A);
}
__global__ __launch_bounds__(512, 2)
void k_gemm_s(const short* A, const float* W1, const float* Wg, float* P)
{
    __shared__ SmemAll sm;
    phase_gemm(blockIdx.x, threadIdx.x, sm.g, A, W1, Wg, P);
}
__global__ __launch_bounds__(512)
void k_tail_s(const float* P, const float* b1, const float* bg,
              const float* W2, const float* b2, float* out)
{
    __shared__ SmemAll sm;
    phase_tail(blockIdx.x, threadIdx.x, sm.t, P, b1, bg, W2, b2, out);
}

extern "C" void kernel_launch(void* const* d_in, const int* in_sizes, int n_in,
                              void* d_out, int out_size, void* d_ws, size_t ws_size,
                              hipStream_t stream)
{
    const float* x    = (const float*)d_in[0];
    const float* mem  = (const float*)d_in[1];
    const int*   tim  = (const int*)d_in[2];
    const float* msur = (const float*)d_in[3];
    const float* lp   = (const float*)d_in[4];
    const float* W1   = (const float*)d_in[5];
    const float* b1   = (const float*)d_in[6];
    const float* Wg   = (const float*)d_in[7];
    const float* bg   = (const float*)d_in[8];
    const float* W2   = (const float*)d_in[9];
    const float* b2   = (const float*)d_in[10];
    float* out = (float*)d_out;

    // ws layout: A bf16 [256][35840] | P fp32 [16][256][2048]
    short* A = (short*)d_ws;
    float* P = (float*)((char*)d_ws + 18350080);

    int coop = 0;
    int dev = 0;
    hipGetDevice(&dev);
    hipDeviceGetAttribute(&coop, hipDeviceAttributeCooperativeLaunch, dev);

    if (coop) {
        void* kargs[] = { (void*)&x, (void*)&mem, (void*)&tim, (void*)&msur,
                          (void*)&lp, (void*)&W1, (void*)&b1, (void*)&Wg,
                          (void*)&bg, (void*)&W2, (void*)&b2, (void*)&A,
                          (void*)&P,  (void*)&out };
        hipError_t e = hipLaunchCooperativeKernel(
            reinterpret_cast<void*>(k_fused), dim3(256), dim3(512),
            kargs, 0, stream);
        if (e == hipSuccess) return;
    }
    // fallback: three sequential launches
    k_build_s<<<256, 512, 0, stream>>>(x, mem, tim, msur, lp, A);
    k_gemm_s <<<256, 512, 0, stream>>>(A, W1, Wg, P);
    k_tail_s <<<256, 512, 0, stream>>>(P, b1, bg, W2, b2, out);
}